// Round 1
// baseline (49.731 us; speedup 1.0000x reference)
//
#include <hip/hip_runtime.h>
#include <hip/hip_bf16.h>

typedef __attribute__((ext_vector_type(8))) short short8;
typedef __attribute__((ext_vector_type(4))) float f32x4;

#define NUM_EMB 512
#define DIM 64
#define SPW 16384   // T*H*W = 16*32*32 spatial positions per batch
#define XPAD 72     // LDS row stride in shorts (64 + 8 pad, keeps 16B alignment)

__device__ __forceinline__ short to_bf16(float f) {
  union { float f; unsigned u; } v;
  v.f = f;
  unsigned r = (v.u + 0x7FFFu + ((v.u >> 16) & 1u)) >> 16;  // RNE
  return (short)(r & 0xFFFFu);
}

// ---------------- prep kernels: bf16 MFMA fragments of E + row norms ----------------
// A1: E as A-operand for S = E * X.   A[row=k_emb][k=d]
// layout: a1[((m*2+s)*64 + lane)*8 + i] = E[m*16 + (lane&15)][s*32 + (lane>>4)*8 + i]
__global__ void prep_a1(const float* __restrict__ emb, short8* __restrict__ a1) {
  int f = blockIdx.x * 256 + threadIdx.x;  // [0, 4096)
  int l = f & 63;
  int s = (f >> 6) & 1;
  int m = f >> 7;
  int row = m * 16 + (l & 15);
  int col0 = s * 32 + (l >> 4) * 8;
  short8 v;
  #pragma unroll
  for (int i = 0; i < 8; ++i) v[i] = to_bf16(emb[row * DIM + col0 + i]);
  a1[f] = v;
}

// A2: E^T as A-operand for Num = E^T * P.   A[row=d][k=k_emb]
// layout: a2[((m*16+s)*64 + lane)*8 + i] = E[s*32 + (lane>>4)*8 + i][m*16 + (lane&15)]
__global__ void prep_a2(const float* __restrict__ emb, short8* __restrict__ a2) {
  int f = blockIdx.x * 256 + threadIdx.x;  // [0, 4096)
  int l = f & 63;
  int s = (f >> 6) & 15;
  int m = f >> 10;
  int col = m * 16 + (l & 15);
  int row0 = s * 32 + (l >> 4) * 8;
  short8 v;
  #pragma unroll
  for (int i = 0; i < 8; ++i) v[i] = to_bf16(emb[(row0 + i) * DIM + col]);
  a2[f] = v;
}

__global__ void prep_norms(const float* __restrict__ emb, float* __restrict__ norms) {
  int k = blockIdx.x * 256 + threadIdx.x;  // [0, 512)
  float acc = 0.f;
  #pragma unroll
  for (int d = 0; d < DIM; ++d) { float e = emb[k * DIM + d]; acc += e * e; }
  norms[k] = acc;
}

// ---------------- main kernel ----------------
// Per block: 64 spatial columns. logits s_k = ||e_k||^2 - 2 x.e_k  (||x||^2 dropped:
// softmax shift-invariant). |s| <= ~0.35 so exp needs no max subtraction.
// One pass: Num[d][n] += exp(s)*E[k][d] via MFMA, Den[n] += exp(s); out = Num/Den.
__global__ __launch_bounds__(256) void vq_main(
    const float* __restrict__ x, const short8* __restrict__ a1,
    const short8* __restrict__ a2, const float* __restrict__ norms,
    float* __restrict__ out) {
  __shared__ __align__(16) short Xl[64 * XPAD];        // X^T tile [n][d] bf16
  __shared__ __align__(16) short Pl[2][64 * XPAD];     // P^T [n][k_local] bf16, dbuf
  __shared__ float denl[4][64];

  const int t = threadIdx.x;
  const int lane = t & 63;
  const int w = t >> 6;        // wave 0..3
  const int l15 = lane & 15;
  const int g = lane >> 4;

  const int tile = blockIdx.x * 64;
  const int b = tile >> 14;          // tile / 16384
  const int off = tile & 16383;
  const float* xb = x + (size_t)b * DIM * SPW + off;
  float* ob = out + (size_t)b * DIM * SPW + off;

  // stage X tile: global [d][n] fp32 -> LDS [n][d] bf16 (coalesced float4 reads)
  {
    const int n0 = 4 * (t & 15);
    const int dbase = t >> 4;
    #pragma unroll
    for (int r = 0; r < 4; ++r) {
      const int d = r * 16 + dbase;
      const float4 v = *reinterpret_cast<const float4*>(xb + (size_t)d * SPW + n0);
      Xl[(n0 + 0) * XPAD + d] = to_bf16(v.x);
      Xl[(n0 + 1) * XPAD + d] = to_bf16(v.y);
      Xl[(n0 + 2) * XPAD + d] = to_bf16(v.z);
      Xl[(n0 + 3) * XPAD + d] = to_bf16(v.w);
    }
  }
  __syncthreads();

  // X B-fragments are identical for every chunk: load once, keep in registers.
  // B[k=d][col=n]: lane holds 8 consecutive d at row n = j*16 + (lane&15).
  short8 bx[4][2];
  #pragma unroll
  for (int j = 0; j < 4; ++j)
    #pragma unroll
    for (int s = 0; s < 2; ++s)
      bx[j][s] = *reinterpret_cast<const short8*>(
          &Xl[(j * 16 + l15) * XPAD + s * 32 + g * 8]);

  f32x4 nacc[4];
  #pragma unroll
  for (int j = 0; j < 4; ++j) nacc[j] = f32x4{0.f, 0.f, 0.f, 0.f};
  float denp[4] = {0.f, 0.f, 0.f, 0.f};

  for (int c = 0; c < 8; ++c) {
    short* plb = &Pl[c & 1][0];
    // E fragments from ws (L2-resident, 128 KB hot)
    const short8 a1f0 = a1[((c * 4 + w) * 2 + 0) * 64 + lane];
    const short8 a1f1 = a1[((c * 4 + w) * 2 + 1) * 64 + lane];
    const short8 a2f0 = a2[(w * 16 + c * 2 + 0) * 64 + lane];
    const short8 a2f1 = a2[(w * 16 + c * 2 + 1) * 64 + lane];
    const float4 nv = *reinterpret_cast<const float4*>(&norms[c * 64 + w * 16 + g * 4]);

    // matmul1: S_chunk[w*16..][n] = E_chunk * X ; C layout: col=lane&15, row=(lane>>4)*4+r
    #pragma unroll
    for (int j = 0; j < 4; ++j) {
      f32x4 z = {0.f, 0.f, 0.f, 0.f};
      z = __builtin_amdgcn_mfma_f32_16x16x32_bf16(a1f0, bx[j][0], z, 0, 0, 0);
      z = __builtin_amdgcn_mfma_f32_16x16x32_bf16(a1f1, bx[j][1], z, 0, 0, 0);
      const float p0 = __expf(nv.x - 2.f * z[0]);
      const float p1 = __expf(nv.y - 2.f * z[1]);
      const float p2 = __expf(nv.z - 2.f * z[2]);
      const float p3 = __expf(nv.w - 2.f * z[3]);
      denp[j] += (p0 + p1) + (p2 + p3);
      const int n = j * 16 + l15;
      const int k = w * 16 + g * 4;
      const unsigned q0 = (unsigned)(unsigned short)to_bf16(p0) |
                          ((unsigned)(unsigned short)to_bf16(p1) << 16);
      const unsigned q1 = (unsigned)(unsigned short)to_bf16(p2) |
                          ((unsigned)(unsigned short)to_bf16(p3) << 16);
      *reinterpret_cast<unsigned*>(&plb[n * XPAD + k])     = q0;
      *reinterpret_cast<unsigned*>(&plb[n * XPAD + k + 2]) = q1;
    }
    __syncthreads();  // P chunk visible to all waves; also fences WAR for buf^1 (dbuf)

    // matmul2: Num[d=w*16..][n] += E^T_chunk * P_chunk
    #pragma unroll
    for (int j = 0; j < 4; ++j) {
      const short8 pb0 = *reinterpret_cast<const short8*>(
          &plb[(j * 16 + l15) * XPAD + g * 8]);
      const short8 pb1 = *reinterpret_cast<const short8*>(
          &plb[(j * 16 + l15) * XPAD + 32 + g * 8]);
      nacc[j] = __builtin_amdgcn_mfma_f32_16x16x32_bf16(a2f0, pb0, nacc[j], 0, 0, 0);
      nacc[j] = __builtin_amdgcn_mfma_f32_16x16x32_bf16(a2f1, pb1, nacc[j], 0, 0, 0);
    }
  }

  // Den[n]: reduce per-thread partials over the 4 lane-groups, then across waves via LDS
  #pragma unroll
  for (int j = 0; j < 4; ++j) {
    denp[j] += __shfl_xor(denp[j], 16, 64);
    denp[j] += __shfl_xor(denp[j], 32, 64);
  }
  if (lane < 16) {
    #pragma unroll
    for (int j = 0; j < 4; ++j) denl[w][j * 16 + lane] = denp[j];
  }
  __syncthreads();

  #pragma unroll
  for (int j = 0; j < 4; ++j) {
    const int n = j * 16 + l15;
    const float den = denl[0][n] + denl[1][n] + denl[2][n] + denl[3][n];
    const float rd = 1.0f / den;
    #pragma unroll
    for (int r = 0; r < 4; ++r) {
      const int d = w * 16 + g * 4 + r;
      ob[(size_t)d * SPW + n] = nacc[j][r] * rd;  // output already (B, D, THW) layout
    }
  }
}

extern "C" void kernel_launch(void* const* d_in, const int* in_sizes, int n_in,
                              void* d_out, int out_size, void* d_ws, size_t ws_size,
                              hipStream_t stream) {
  (void)in_sizes; (void)n_in; (void)out_size; (void)ws_size;
  const float* x   = (const float*)d_in[0];   // (8, 64, 16, 32, 32) fp32
  const float* emb = (const float*)d_in[1];   // (512, 64) fp32
  float* out = (float*)d_out;

  char* ws = (char*)d_ws;
  short8* a1   = (short8*)ws;                 // 65536 B
  short8* a2   = (short8*)(ws + 65536);       // 65536 B
  float* norms = (float*)(ws + 131072);       // 2048 B

  prep_a1<<<16, 256, 0, stream>>>(emb, a1);
  prep_a2<<<16, 256, 0, stream>>>(emb, a2);
  prep_norms<<<2, 256, 0, stream>>>(emb, norms);
  vq_main<<<2048, 256, 0, stream>>>(x, a1, a2, norms, out);
}

// Round 3
// 47.028 us; speedup vs baseline: 1.0575x; 1.0575x over previous
//
#include <hip/hip_runtime.h>
#include <hip/hip_bf16.h>

typedef __attribute__((ext_vector_type(8))) short short8;
typedef __attribute__((ext_vector_type(4))) _Float16 half4;
typedef __attribute__((ext_vector_type(4))) float f32x4;

#define SPW 16384   // T*H*W spatial positions per batch
#define XFP 66      // X f32 tile row stride (dwords): 66%32=2 -> 2-way max (free)
#define RP  68      // reduce buffer row stride (dwords)
#define LOG2E 1.4426950408889634f

__device__ __forceinline__ float exp2_hw(float f) {
  return __builtin_amdgcn_exp2f(f);   // v_exp_f32 (base-2)
}

__device__ __forceinline__ short bf16s(float f) {
  union { __hip_bfloat16 h; short s; } u;
  u.h = __float2bfloat16(f);   // single HW cvt (RNE)
  return u.s;
}

// ---------------- prep kernels ----------------
// a1: A-operand frags (16x16x32) of (-2*log2e)*E for S' = (-2 log2e) * E x X
// a1[((m*2+s)*64 + lane)] = row m*16+(lane&15), k-cols s*32+(lane>>4)*8 .. +7
__global__ void prep_a1(const float* __restrict__ emb, short8* __restrict__ a1) {
  int f = blockIdx.x * 256 + threadIdx.x;  // [0, 4096)
  int l = f & 63;
  int s = (f >> 6) & 1;
  int m = f >> 7;
  int row = m * 16 + (l & 15);
  int col0 = s * 32 + (l >> 4) * 8;
  short8 v;
  #pragma unroll
  for (int i = 0; i < 8; ++i)
    v[i] = bf16s(-2.0f * LOG2E * emb[row * 64 + col0 + i]);
  a1[f] = v;
}

// eb: B-operand frags (16x16x16 f16) of E for Num^T += P^T x E
// eb[((c*4+w)*4+m2)*64 + lane] = k rows c*64+w*16+4*(lane>>4)+{0..3}, col m2*16+(lane&15)
__global__ void prep_eb(const float* __restrict__ emb, half4* __restrict__ eb) {
  int f = blockIdx.x * 256 + threadIdx.x;  // [0, 8192)
  int l = f & 63;
  int m2 = (f >> 6) & 3;
  int w = (f >> 8) & 3;
  int c = f >> 10;
  int d = m2 * 16 + (l & 15);
  int k0 = c * 64 + w * 16 + 4 * (l >> 4);
  half4 v;
  #pragma unroll
  for (int i = 0; i < 4; ++i) v[i] = (_Float16)emb[(k0 + i) * 64 + d];
  eb[f] = v;
}

__global__ void prep_norms(const float* __restrict__ emb, float* __restrict__ norms) {
  int k = blockIdx.x * 256 + threadIdx.x;  // [0, 512)
  float acc = 0.f;
  #pragma unroll
  for (int d = 0; d < 64; ++d) { float e = emb[k * 64 + d]; acc += e * e; }
  norms[k] = acc * LOG2E;
}

// ---------------- main kernel ----------------
// logits(base2) = log2e*(||e_k||^2 - 2 x.e_k); ||x||^2 dropped (softmax shift-inv),
// |logit| small -> exp2 needs no max subtraction. Wave w owns k-slice {c*64+w*16..+15}:
// matmul1 C-layout (col=l15, rows 4g+r) IS the A-layout of mfma_16x16x16_f16,
// so P feeds matmul2 with no cross-lane traffic and NO barriers in the main loop.
// Wave partials of Num^T reduced via LDS at the end.
__global__ __launch_bounds__(256, 2) void vq_main(
    const float* __restrict__ x, const short8* __restrict__ a1,
    const half4* __restrict__ eb, const float* __restrict__ norms,
    float* __restrict__ out) {
  __shared__ __align__(16) char lds_raw[18688];
  float* Xf   = reinterpret_cast<float*>(lds_raw);            // [64][66] f32 (phase 1)
  float* Rf   = reinterpret_cast<float*>(lds_raw);            // [64][68] f32 (phase 3)
  float* denl = reinterpret_cast<float*>(lds_raw + 17408);    // [4][64]
  float* rden = reinterpret_cast<float*>(lds_raw + 18432);    // [64]

  const int t = threadIdx.x;
  const int lane = t & 63;
  const int w = t >> 6;
  const int l15 = lane & 15;
  const int g = lane >> 4;

  const int tile = blockIdx.x * 64;
  const int b = tile >> 14;
  const int off = tile & 16383;
  const float* xb = x + (size_t)b * (64 * SPW) + off;
  float* ob = out + (size_t)b * (64 * SPW) + off;

  // stage X tile: global [d][n] fp32 -> LDS [d][n] fp32, stride 66 dwords
  {
    const int n0 = 4 * (t & 15);
    const int dq = t >> 4;
    #pragma unroll
    for (int r = 0; r < 4; ++r) {
      const int d = r * 16 + dq;
      const float4 v = *reinterpret_cast<const float4*>(xb + (size_t)d * SPW + n0);
      *reinterpret_cast<float2*>(&Xf[d * XFP + n0])     = make_float2(v.x, v.y);
      *reinterpret_cast<float2*>(&Xf[d * XFP + n0 + 2]) = make_float2(v.z, v.w);
    }
  }
  __syncthreads();

  // bx: B-frags of matmul1 (k=d contiguous 8 per lane at col n=j*16+l15), bf16
  short8 bx[4][2];
  #pragma unroll
  for (int j = 0; j < 4; ++j) {
    const int n = j * 16 + l15;
    #pragma unroll
    for (int s = 0; s < 2; ++s) {
      short8 v;
      #pragma unroll
      for (int i = 0; i < 8; ++i) {
        const int d = s * 32 + g * 8 + i;
        v[i] = bf16s(Xf[d * XFP + n]);
      }
      bx[j][s] = v;
    }
  }

  f32x4 pacc[4][4];   // [j n-tile][m2 d-tile] partial Num^T, this wave's k-slices
  #pragma unroll
  for (int j = 0; j < 4; ++j)
    #pragma unroll
    for (int m2 = 0; m2 < 4; ++m2) pacc[j][m2] = f32x4{0.f, 0.f, 0.f, 0.f};
  float denp[4] = {0.f, 0.f, 0.f, 0.f};

  for (int c = 0; c < 8; ++c) {
    const short8 a1f0 = a1[((c * 4 + w) * 2 + 0) * 64 + lane];
    const short8 a1f1 = a1[((c * 4 + w) * 2 + 1) * 64 + lane];
    half4 ebf[4];
    #pragma unroll
    for (int m2 = 0; m2 < 4; ++m2) ebf[m2] = eb[((c * 4 + w) * 4 + m2) * 64 + lane];
    const float4 nv = *reinterpret_cast<const float4*>(&norms[c * 64 + w * 16 + g * 4]);

    #pragma unroll
    for (int j = 0; j < 4; ++j) {
      f32x4 z = {0.f, 0.f, 0.f, 0.f};
      z = __builtin_amdgcn_mfma_f32_16x16x32_bf16(a1f0, bx[j][0], z, 0, 0, 0);
      z = __builtin_amdgcn_mfma_f32_16x16x32_bf16(a1f1, bx[j][1], z, 0, 0, 0);
      const float p0 = exp2_hw(nv.x + z[0]);
      const float p1 = exp2_hw(nv.y + z[1]);
      const float p2 = exp2_hw(nv.z + z[2]);
      const float p3 = exp2_hw(nv.w + z[3]);
      denp[j] += (p0 + p1) + (p2 + p3);
      const half4 pa = {(_Float16)p0, (_Float16)p1, (_Float16)p2, (_Float16)p3};
      #pragma unroll
      for (int m2 = 0; m2 < 4; ++m2)
        pacc[j][m2] = __builtin_amdgcn_mfma_f32_16x16x16f16(pa, ebf[m2], pacc[j][m2], 0, 0, 0);
    }
  }

  // den: reduce over lane-groups (k within wave), then across waves via LDS
  #pragma unroll
  for (int j = 0; j < 4; ++j) {
    denp[j] += __shfl_xor(denp[j], 16, 64);
    denp[j] += __shfl_xor(denp[j], 32, 64);
  }
  if (lane < 16) {
    #pragma unroll
    for (int j = 0; j < 4; ++j) denl[w * 64 + j * 16 + lane] = denp[j];
  }
  __syncthreads();
  if (t < 64) {
    const float s = denl[t] + denl[64 + t] + denl[128 + t] + denl[192 + t];
    rden[t] = 1.0f / s;
  }

  // Num reduce across waves + coalesced store, one j-tile (16 n) at a time
  const int n16 = t & 15;
  const int dq2 = t >> 4;
  #pragma unroll
  for (int j = 0; j < 4; ++j) {
    __syncthreads();  // j=0: Xf dead + rden ready; j>0: WAR on Rf
    // pacc C-layout: col d=m2*16+l15, row n16=4g+r  ->  Rf[w*16 + n16][d]
    #pragma unroll
    for (int m2 = 0; m2 < 4; ++m2)
      #pragma unroll
      for (int r = 0; r < 4; ++r)
        Rf[(w * 16 + 4 * g + r) * RP + m2 * 16 + l15] = pacc[j][m2][r];
    __syncthreads();
    const float rdv = rden[j * 16 + n16];
    #pragma unroll
    for (int r = 0; r < 4; ++r) {
      const int dd = r * 16 + dq2;
      const float sum = (Rf[(n16)*RP + dd] + Rf[(16 + n16) * RP + dd])
                      + (Rf[(32 + n16) * RP + dd] + Rf[(48 + n16) * RP + dd]);
      ob[(size_t)dd * SPW + j * 16 + n16] = sum * rdv;
    }
  }
}

extern "C" void kernel_launch(void* const* d_in, const int* in_sizes, int n_in,
                              void* d_out, int out_size, void* d_ws, size_t ws_size,
                              hipStream_t stream) {
  (void)in_sizes; (void)n_in; (void)out_size; (void)ws_size;
  const float* x   = (const float*)d_in[0];   // (8, 64, 16, 32, 32) fp32
  const float* emb = (const float*)d_in[1];   // (512, 64) fp32
  float* out = (float*)d_out;

  char* ws = (char*)d_ws;
  short8* a1   = (short8*)ws;                 // 65536 B
  half4*  eb   = (half4*)(ws + 65536);        // 65536 B
  float*  norms = (float*)(ws + 131072);      // 2048 B

  prep_a1<<<16, 256, 0, stream>>>(emb, a1);
  prep_eb<<<32, 256, 0, stream>>>(emb, eb);
  prep_norms<<<2, 256, 0, stream>>>(emb, norms);
  vq_main<<<2048, 256, 0, stream>>>(x, a1, eb, norms, out);
}